// Round 14
// baseline (294.158 us; speedup 1.0000x reference)
//
#include <hip/hip_runtime.h>

#define DIM 256
#define DOUT 64
#define PSPLITS 16

typedef short bf16x8 __attribute__((ext_vector_type(8)));
typedef float f32x4 __attribute__((ext_vector_type(4)));
typedef unsigned short u16x8 __attribute__((ext_vector_type(8)));

// ---- bf16 helpers (bit-level, RNE) ----
static __device__ __forceinline__ float b2f(unsigned short u) {
    return __uint_as_float(((unsigned)u) << 16);
}
static __device__ __forceinline__ unsigned short f2bf(float f) {
    unsigned u = __float_as_uint(f);
    unsigned r = (u + 0x7fffu + ((u >> 16) & 1u)) >> 16;
    return (unsigned short)r;
}

// ---------------- convert x (f32) -> h (bf16) ----------------
__global__ void cvt_f32_bf16(const float4* __restrict__ src, ushort4* __restrict__ dst, int n4) {
    int i = blockIdx.x * blockDim.x + threadIdx.x;
    int stride = gridDim.x * blockDim.x;
    for (; i < n4; i += stride) {
        float4 v = src[i];
        ushort4 o;
        o.x = f2bf(v.x); o.y = f2bf(v.y); o.z = f2bf(v.z); o.w = f2bf(v.w);
        dst[i] = o;
    }
}

// ---------------- CSR build ----------------
__global__ void hist_kernel(const int* __restrict__ dst, int* __restrict__ deg, int E) {
    int i = blockIdx.x * blockDim.x + threadIdx.x;
    if (i < E) atomicAdd(&deg[dst[i]], 1);
}

__global__ void scan_blocksum(const int* __restrict__ deg, int* __restrict__ bsum, int n) {
    __shared__ int s[256];
    int t = threadIdx.x;
    int i = blockIdx.x * 256 + t;
    s[t] = (i < n) ? deg[i] : 0;
    __syncthreads();
    for (int off = 128; off > 0; off >>= 1) {
        if (t < off) s[t] += s[t + off];
        __syncthreads();
    }
    if (t == 0) bsum[blockIdx.x] = s[0];
}

__global__ void scan_partials(int* __restrict__ bsum, int* __restrict__ row_ptr,
                              int nb, int n) {
    __shared__ int s[256];
    int t = threadIdx.x;
    int v = (t < nb) ? bsum[t] : 0;
    s[t] = v;
    __syncthreads();
    for (int off = 1; off < 256; off <<= 1) {
        int u = (t >= off) ? s[t - off] : 0;
        __syncthreads();
        s[t] += u;
        __syncthreads();
    }
    if (t < nb) bsum[t] = s[t] - v;          // exclusive
    if (t == 255) row_ptr[n] = s[255];       // total == E
}

__global__ void scan_final(int* __restrict__ deg, int* __restrict__ row_ptr,
                           const int* __restrict__ bsum, int n) {
    __shared__ int s[256];
    int t = threadIdx.x;
    int i = blockIdx.x * 256 + t;
    int d = (i < n) ? deg[i] : 0;
    s[t] = d;
    __syncthreads();
    for (int off = 1; off < 256; off <<= 1) {
        int u = (t >= off) ? s[t - off] : 0;
        __syncthreads();
        s[t] += u;
        __syncthreads();
    }
    if (i < n) {
        int val = bsum[blockIdx.x] + s[t] - d;   // exclusive prefix
        row_ptr[i] = val;
        deg[i] = val;                            // scatter cursor
    }
}

__global__ void scatter_kernel(const int* __restrict__ src, const int* __restrict__ dst,
                               int* __restrict__ cursor, int* __restrict__ perm, int E) {
    int i = blockIdx.x * blockDim.x + threadIdx.x;
    if (i < E) {
        int d = dst[i];
        int p = atomicAdd(&cursor[d], 1);
        perm[p] = src[i];
    }
}

// ---------------- transpose + convert W [K][N] f32 -> Wt [N][K] bf16 ----------------
__global__ void transpose_w(const float* __restrict__ W, unsigned short* __restrict__ Wt) {
    __shared__ float tile[32][33];
    int l = blockIdx.z;
    int k0 = blockIdx.x * 32, n0 = blockIdx.y * 32;
    const float* Wl = W + (size_t)l * DIM * DIM;
    unsigned short* Wtl = Wt + (size_t)l * DIM * DIM;
    int tx = threadIdx.x, ty = threadIdx.y;
    for (int i = ty; i < 32; i += 8)
        tile[i][tx] = Wl[(size_t)(k0 + i) * DIM + n0 + tx];
    __syncthreads();
    for (int i = ty; i < 32; i += 8)
        Wtl[(size_t)(n0 + i) * DIM + k0 + tx] = f2bf(tile[tx][i]);
}

// ---------------- aggregation (bf16): z = h + sum_{e: dst=n} h[src[e]] ----------------
__global__ void agg_kernel(const unsigned short* __restrict__ H, const int* __restrict__ row_ptr,
                           const int* __restrict__ perm, unsigned short* __restrict__ Z, int n) {
    int wave = threadIdx.x >> 6;
    int lane = threadIdx.x & 63;
    int node = blockIdx.x * 4 + wave;
    if (node >= n) return;
    const int half = lane >> 5;
    const int sl = lane & 31;
    const u16x8* hb = (const u16x8*)H;
    float acc[8];
    {
        u16x8 own = hb[(size_t)node * 32 + sl];
#pragma unroll
        for (int q = 0; q < 8; ++q) acc[q] = half ? 0.f : b2f(own[q]);
    }
    const int lo = row_ptr[node], hi = row_ptr[node + 1];
    int e = lo + half;
    for (; e + 14 < hi; e += 16) {
        u16x8 v[8];
#pragma unroll
        for (int j = 0; j < 8; ++j)
            v[j] = hb[(size_t)perm[e + 2 * j] * 32 + sl];
#pragma unroll
        for (int j = 0; j < 8; ++j)
#pragma unroll
            for (int q = 0; q < 8; ++q) acc[q] += b2f(v[j][q]);
    }
    for (; e + 6 < hi; e += 8) {
        u16x8 v[4];
#pragma unroll
        for (int j = 0; j < 4; ++j)
            v[j] = hb[(size_t)perm[e + 2 * j] * 32 + sl];
#pragma unroll
        for (int j = 0; j < 4; ++j)
#pragma unroll
            for (int q = 0; q < 8; ++q) acc[q] += b2f(v[j][q]);
    }
    for (; e < hi; e += 2) {
        u16x8 v = hb[(size_t)perm[e] * 32 + sl];
#pragma unroll
        for (int q = 0; q < 8; ++q) acc[q] += b2f(v[q]);
    }
#pragma unroll
    for (int q = 0; q < 8; ++q) acc[q] += __shfl_xor(acc[q], 32);
    if (half == 0) {
        u16x8 o;
#pragma unroll
        for (int q = 0; q < 8; ++q) o[q] = f2bf(acc[q]);
        ((u16x8*)Z)[(size_t)node * 32 + sl] = o;
    }
}

// ---------------- persistent reg-B bf16 MFMA GEMM (LDS-free) ----------------
// Grid = 512 blocks (2/CU). Block b: W-half = b&1, mslice = b>>1 (0..255).
// Wave w: n-panel = half*128 + (w&1)*64, loaded DIRECTLY global->reg (L2-resident,
// no LDS, no barrier); m-tiles t = mslice*2+(w>>1) + 512*i.
template <bool RELU>
__global__ __launch_bounds__(256, 2) void mfma_gemm(const unsigned short* __restrict__ A,
                                                    const unsigned short* __restrict__ Bt,
                                                    const float* __restrict__ bias,
                                                    unsigned short* __restrict__ C, int M) {
    const int tid = threadIdx.x;
    const int wave = tid >> 6;
    const int lane = tid & 63;
    const int l15 = lane & 15;
    const int g4 = lane >> 4;                  // 0..3
    const int half = blockIdx.x & 1;
    const int mslice = blockIdx.x >> 1;        // 0..255
    const int NT = (M + 15) / 16;

    const int ncol0 = half * 128 + (wave & 1) * 64;

    // ---- reg-cache this wave's 64-col B panel straight from global ----
    bf16x8 b[4][8];
#pragma unroll
    for (int n = 0; n < 4; ++n) {
        const unsigned short* cbase = Bt + (size_t)(ncol0 + n * 16 + l15) * 256;
#pragma unroll
        for (int k8 = 0; k8 < 8; ++k8)
            b[n][k8] = *reinterpret_cast<const bf16x8*>(cbase + k8 * 32 + g4 * 8);
    }

    float bv[4];
#pragma unroll
    for (int n = 0; n < 4; ++n) bv[n] = bias[ncol0 + n * 16 + l15];

    const int base = mslice * 2 + (wave >> 1);

    auto loadA = [&](bf16x8 (&a)[8], int t) {
        int r = t * 16 + l15;
        if (r >= M) r = M - 1;
        const unsigned short* arow = &A[(size_t)r * 256];
#pragma unroll
        for (int k8 = 0; k8 < 8; ++k8)
            a[k8] = *reinterpret_cast<const bf16x8*>(arow + k8 * 32 + g4 * 8);
    };

    auto computeStore = [&](bf16x8 (&a)[8], int t) {
        f32x4 acc[4] = {};
#pragma unroll
        for (int k8 = 0; k8 < 8; ++k8)
#pragma unroll
            for (int n = 0; n < 4; ++n)
                acc[n] = __builtin_amdgcn_mfma_f32_16x16x32_bf16(a[k8], b[n][k8], acc[n], 0, 0, 0);
        int r0 = t * 16 + g4 * 4;
#pragma unroll
        for (int n = 0; n < 4; ++n) {
            int col = ncol0 + n * 16 + l15;
#pragma unroll
            for (int r = 0; r < 4; ++r) {
                int row = r0 + r;
                if (row < M) {
                    float v = acc[n][r] + bv[n];
                    if (RELU) v = fmaxf(v, 0.f);
                    C[(size_t)row * 256 + col] = f2bf(v);
                }
            }
        }
    };

    bf16x8 a0[8], a1[8];
    int t = base;
    if (t >= NT) return;
    loadA(a0, t);
#pragma unroll 1
    for (int rep = 0; rep < 2; ++rep) {
        if (t >= NT) break;
        if (t + 512 < NT) loadA(a1, t + 512);
        computeStore(a0, t);
        t += 512;
        if (t >= NT) break;
        if (t + 512 < NT) loadA(a0, t + 512);
        computeStore(a1, t);
        t += 512;
    }
}

// ---------------- pooling ----------------
__global__ void gstart_kernel(const int* __restrict__ bids, int* __restrict__ gstart,
                              int n, int G) {
    int g = blockIdx.x * blockDim.x + threadIdx.x;
    if (g > G) return;
    if (g == G) { gstart[G] = n; return; }
    int lo = 0, hi = n;
    while (lo < hi) {
        int mid = (lo + hi) >> 1;
        if (bids[mid] < g) lo = mid + 1; else hi = mid;
    }
    gstart[g] = lo;
}

// pools bf16 rows (here: t) into f32 accumulator buffer via atomics
__global__ void pool_kernel(const ushort4* __restrict__ h4, const int* __restrict__ gstart,
                            float* __restrict__ pooled) {
    int g = blockIdx.x;
    int split = blockIdx.y;
    int lane = threadIdx.x;   // 0..63
    int lo = gstart[g], hi = gstart[g + 1];
    int cnt = hi - lo;
    int chunk = (cnt + PSPLITS - 1) / PSPLITS;
    int s0 = lo + split * chunk;
    int s1 = min(s0 + chunk, hi);
    if (s0 >= s1) return;
    float ax = 0.f, ay = 0.f, az = 0.f, aw = 0.f;
    for (int nd = s0; nd < s1; ++nd) {
        ushort4 v = h4[(size_t)nd * 64 + lane];
        ax += b2f(v.x); ay += b2f(v.y); az += b2f(v.z); aw += b2f(v.w);
    }
    float* p = &pooled[(size_t)g * DIM + lane * 4];
    atomicAdd(p + 0, ax);
    atomicAdd(p + 1, ay);
    atomicAdd(p + 2, az);
    atomicAdd(p + 3, aw);
}

// final: pooled = Tp@W2 + cnt*b2 (f32), out = pooled@Wout + bout
__global__ void final_kernel(const float* __restrict__ Tp, const int* __restrict__ gstart,
                             const float* __restrict__ W2, const float* __restrict__ b2,
                             const float* __restrict__ Wout, const float* __restrict__ bout,
                             float* __restrict__ out, float* __restrict__ pooled) {
    __shared__ float tps[DIM];
    __shared__ float pl[DIM];
    int g = blockIdx.x;
    int tidx = threadIdx.x;    // 256
    float cnt = (float)(gstart[g + 1] - gstart[g]);
    tps[tidx] = Tp[(size_t)g * DIM + tidx];
    __syncthreads();
    float acc = cnt * b2[tidx];
    for (int d = 0; d < DIM; ++d)
        acc += tps[d] * W2[(size_t)d * DIM + tidx];
    pooled[(size_t)g * DIM + tidx] = acc;
    pl[tidx] = acc;
    __syncthreads();
    if (tidx < DOUT) {
        float o = bout[tidx];
        for (int d = 0; d < DIM; ++d)
            o += pl[d] * Wout[(size_t)d * DOUT + tidx];
        out[(size_t)g * DOUT + tidx] = o;
    }
}

// ---------------- launch ----------------
extern "C" void kernel_launch(void* const* d_in, const int* in_sizes, int n_in,
                              void* d_out, int out_size, void* d_ws, size_t ws_size,
                              hipStream_t stream) {
    const float* x    = (const float*)d_in[0];
    const int*   esrc = (const int*)d_in[1];
    const int*   edst = (const int*)d_in[2];
    const int*   bids = (const int*)d_in[3];
    const float* W1   = (const float*)d_in[4];
    const float* b1   = (const float*)d_in[5];
    const float* W2   = (const float*)d_in[6];
    const float* b2   = (const float*)d_in[7];
    const float* Wout = (const float*)d_in[8];
    const float* bout = (const float*)d_in[9];

    const int N = in_sizes[3];             // 20000
    const int E = in_sizes[1];             // 320000
    const int L = in_sizes[5] / DIM;       // 4
    const int G = out_size / (DOUT + DIM); // 128
    const int NB = (N + 255) / 256;        // scan blocks (79)

    char* ws = (char*)d_ws;
    size_t off = 0;
    auto carve = [&](size_t bytes) -> char* {
        char* p = ws + off;
        off = (off + bytes + 255) & ~(size_t)255;
        return p;
    };
    int* row_ptr = (int*)carve((size_t)(N + 1) * sizeof(int));
    int* cursor  = (int*)carve((size_t)N * sizeof(int));
    int* perm    = (int*)carve((size_t)E * sizeof(int));
    int* gstart  = (int*)carve((size_t)(G + 1) * sizeof(int));
    int* bsum    = (int*)carve((size_t)256 * sizeof(int));
    float* Tp    = (float*)carve((size_t)G * DIM * sizeof(float));
    unsigned short* h   = (unsigned short*)carve((size_t)N * DIM * 2);
    unsigned short* z   = (unsigned short*)carve((size_t)N * DIM * 2);
    unsigned short* t   = (unsigned short*)carve((size_t)N * DIM * 2);
    unsigned short* wt1 = (unsigned short*)carve((size_t)L * DIM * DIM * 2);
    unsigned short* wt2 = (unsigned short*)carve((size_t)L * DIM * DIM * 2);
    (void)ws_size;

    // h = bf16(x)
    cvt_f32_bf16<<<2048, 256, 0, stream>>>((const float4*)x, (ushort4*)h, N * (DIM / 4));

    // CSR build: hist -> 3-phase parallel scan -> scatter
    hipMemsetAsync(cursor, 0, (size_t)N * sizeof(int), stream);
    hist_kernel<<<(E + 255) / 256, 256, 0, stream>>>(edst, cursor, E);
    scan_blocksum<<<NB, 256, 0, stream>>>(cursor, bsum, N);
    scan_partials<<<1, 256, 0, stream>>>(bsum, row_ptr, NB, N);
    scan_final<<<NB, 256, 0, stream>>>(cursor, row_ptr, bsum, N);
    scatter_kernel<<<(E + 255) / 256, 256, 0, stream>>>(esrc, edst, cursor, perm, E);

    // Wt = bf16(W^T) for both MLP weight sets
    {
        dim3 tgrid(DIM / 32, DIM / 32, L);
        dim3 tblk(32, 8);
        transpose_w<<<tgrid, tblk, 0, stream>>>(W1, wt1);
        transpose_w<<<tgrid, tblk, 0, stream>>>(W2, wt2);
    }

    for (int l = 0; l < L; ++l) {
        agg_kernel<<<(N + 3) / 4, 256, 0, stream>>>(h, row_ptr, perm, z, N);
        mfma_gemm<true><<<512, 256, 0, stream>>>(
            z, wt1 + (size_t)l * DIM * DIM, b1 + (size_t)l * DIM, t, N);
        if (l < L - 1)
            mfma_gemm<true><<<512, 256, 0, stream>>>(
                t, wt2 + (size_t)l * DIM * DIM, b2 + (size_t)l * DIM, h, N);
        // last layer: GEMM2 folded into pooled path (linearity of segment_sum)
    }

    float* outp   = (float*)d_out;
    float* pooled = outp + (size_t)G * DOUT;
    hipMemsetAsync(Tp, 0, (size_t)G * DIM * sizeof(float), stream);
    gstart_kernel<<<1, 256, 0, stream>>>(bids, gstart, N, G);
    {
        dim3 pgrid(G, PSPLITS);
        pool_kernel<<<pgrid, 64, 0, stream>>>((const ushort4*)t, gstart, Tp);
    }
    final_kernel<<<G, 256, 0, stream>>>(Tp, gstart,
                                        W2 + (size_t)(L - 1) * DIM * DIM,
                                        b2 + (size_t)(L - 1) * DIM,
                                        Wout, bout, outp, pooled);
}

// Round 15
// 248.225 us; speedup vs baseline: 1.1850x; 1.1850x over previous
//
#include <hip/hip_runtime.h>

#define DIM 256
#define DOUT 64
#define PSPLITS 16

typedef short bf16x8 __attribute__((ext_vector_type(8)));
typedef float f32x4 __attribute__((ext_vector_type(4)));
typedef unsigned short u16x8 __attribute__((ext_vector_type(8)));

// ---- bf16 helpers (bit-level, RNE) ----
static __device__ __forceinline__ float b2f(unsigned short u) {
    return __uint_as_float(((unsigned)u) << 16);
}
static __device__ __forceinline__ unsigned short f2bf(float f) {
    unsigned u = __float_as_uint(f);
    unsigned r = (u + 0x7fffu + ((u >> 16) & 1u)) >> 16;
    return (unsigned short)r;
}

// ---------------- convert x (f32) -> h (bf16), and zero CSR cursor ----------------
__global__ void cvt_zero_kernel(const float4* __restrict__ src, ushort4* __restrict__ dst,
                                int n4, int* __restrict__ cursor, int ncur) {
    int i = blockIdx.x * blockDim.x + threadIdx.x;
    if (i < ncur) cursor[i] = 0;
    int stride = gridDim.x * blockDim.x;
    for (int j = i; j < n4; j += stride) {
        float4 v = src[j];
        ushort4 o;
        o.x = f2bf(v.x); o.y = f2bf(v.y); o.z = f2bf(v.z); o.w = f2bf(v.w);
        dst[j] = o;
    }
}

// ---------------- CSR build ----------------
__global__ void hist_kernel(const int* __restrict__ dst, int* __restrict__ deg, int E) {
    int i = blockIdx.x * blockDim.x + threadIdx.x;
    if (i < E) atomicAdd(&deg[dst[i]], 1);
}

__global__ void scan_blocksum(const int* __restrict__ deg, int* __restrict__ bsum, int n) {
    __shared__ int s[256];
    int t = threadIdx.x;
    int i = blockIdx.x * 256 + t;
    s[t] = (i < n) ? deg[i] : 0;
    __syncthreads();
    for (int off = 128; off > 0; off >>= 1) {
        if (t < off) s[t] += s[t + off];
        __syncthreads();
    }
    if (t == 0) bsum[blockIdx.x] = s[0];
}

// single block: scan <=256 partials; ALSO does graph-start binary searches (gstart)
__global__ void scan_partials(int* __restrict__ bsum, int* __restrict__ row_ptr,
                              int nb, int n, const int* __restrict__ bids,
                              int* __restrict__ gstart, int G) {
    __shared__ int s[256];
    int t = threadIdx.x;
    int v = (t < nb) ? bsum[t] : 0;
    s[t] = v;
    __syncthreads();
    for (int off = 1; off < 256; off <<= 1) {
        int u = (t >= off) ? s[t - off] : 0;
        __syncthreads();
        s[t] += u;
        __syncthreads();
    }
    if (t < nb) bsum[t] = s[t] - v;          // exclusive
    if (t == 255) row_ptr[n] = s[255];       // total == E
    // gstart: thread g in [0..G]
    if (t <= G) {
        if (t == G) gstart[G] = n;
        else {
            int lo = 0, hi = n;
            while (lo < hi) {
                int mid = (lo + hi) >> 1;
                if (bids[mid] < t) lo = mid + 1; else hi = mid;
            }
            gstart[t] = lo;
        }
    }
}

// per-block local exclusive scan + block offset -> row_ptr & cursor; also zero Tp
__global__ void scan_final(int* __restrict__ deg, int* __restrict__ row_ptr,
                           const int* __restrict__ bsum, int n,
                           float* __restrict__ Tp, int ntp) {
    __shared__ int s[256];
    int t = threadIdx.x;
    int i = blockIdx.x * 256 + t;
    int d = (i < n) ? deg[i] : 0;
    s[t] = d;
    __syncthreads();
    for (int off = 1; off < 256; off <<= 1) {
        int u = (t >= off) ? s[t - off] : 0;
        __syncthreads();
        s[t] += u;
        __syncthreads();
    }
    if (i < n) {
        int val = bsum[blockIdx.x] + s[t] - d;   // exclusive prefix
        row_ptr[i] = val;
        deg[i] = val;                            // scatter cursor
    }
    for (int j = i; j < ntp; j += gridDim.x * 256) Tp[j] = 0.f;
}

__global__ void scatter_kernel(const int* __restrict__ src, const int* __restrict__ dst,
                               int* __restrict__ cursor, int* __restrict__ perm, int E) {
    int i = blockIdx.x * blockDim.x + threadIdx.x;
    if (i < E) {
        int d = dst[i];
        int p = atomicAdd(&cursor[d], 1);
        perm[p] = src[i];
    }
}

// ---------------- transpose + convert both weight sets in one dispatch ----------------
// z in [0, 2L): z < L -> W1 layer z; else W2 layer z-L
__global__ void transpose_all(const float* __restrict__ W1, unsigned short* __restrict__ Wt1,
                              const float* __restrict__ W2, unsigned short* __restrict__ Wt2,
                              int L) {
    __shared__ float tile[32][33];
    int zz = blockIdx.z;
    const float* Wl;
    unsigned short* Wtl;
    if (zz < L) { Wl = W1 + (size_t)zz * DIM * DIM; Wtl = Wt1 + (size_t)zz * DIM * DIM; }
    else { Wl = W2 + (size_t)(zz - L) * DIM * DIM; Wtl = Wt2 + (size_t)(zz - L) * DIM * DIM; }
    int k0 = blockIdx.x * 32, n0 = blockIdx.y * 32;
    int tx = threadIdx.x, ty = threadIdx.y;
    for (int i = ty; i < 32; i += 8)
        tile[i][tx] = Wl[(size_t)(k0 + i) * DIM + n0 + tx];
    __syncthreads();
    for (int i = ty; i < 32; i += 8)
        Wtl[(size_t)(n0 + i) * DIM + k0 + tx] = f2bf(tile[tx][i]);
}

// ---------------- aggregation (bf16): z = h + sum_{e: dst=n} h[src[e]] ----------------
__global__ void agg_kernel(const unsigned short* __restrict__ H, const int* __restrict__ row_ptr,
                           const int* __restrict__ perm, unsigned short* __restrict__ Z, int n) {
    int wave = threadIdx.x >> 6;
    int lane = threadIdx.x & 63;
    int node = blockIdx.x * 4 + wave;
    if (node >= n) return;
    const int half = lane >> 5;
    const int sl = lane & 31;
    const u16x8* hb = (const u16x8*)H;
    float acc[8];
    {
        u16x8 own = hb[(size_t)node * 32 + sl];
#pragma unroll
        for (int q = 0; q < 8; ++q) acc[q] = half ? 0.f : b2f(own[q]);
    }
    const int lo = row_ptr[node], hi = row_ptr[node + 1];
    int e = lo + half;
    for (; e + 14 < hi; e += 16) {
        u16x8 v[8];
#pragma unroll
        for (int j = 0; j < 8; ++j)
            v[j] = hb[(size_t)perm[e + 2 * j] * 32 + sl];
#pragma unroll
        for (int j = 0; j < 8; ++j)
#pragma unroll
            for (int q = 0; q < 8; ++q) acc[q] += b2f(v[j][q]);
    }
    for (; e + 6 < hi; e += 8) {
        u16x8 v[4];
#pragma unroll
        for (int j = 0; j < 4; ++j)
            v[j] = hb[(size_t)perm[e + 2 * j] * 32 + sl];
#pragma unroll
        for (int j = 0; j < 4; ++j)
#pragma unroll
            for (int q = 0; q < 8; ++q) acc[q] += b2f(v[j][q]);
    }
    for (; e < hi; e += 2) {
        u16x8 v = hb[(size_t)perm[e] * 32 + sl];
#pragma unroll
        for (int q = 0; q < 8; ++q) acc[q] += b2f(v[q]);
    }
#pragma unroll
    for (int q = 0; q < 8; ++q) acc[q] += __shfl_xor(acc[q], 32);
    if (half == 0) {
        u16x8 o;
#pragma unroll
        for (int q = 0; q < 8; ++q) o[q] = f2bf(acc[q]);
        ((u16x8*)Z)[(size_t)node * 32 + sl] = o;
    }
}

// ---------------- persistent reg-B bf16 MFMA GEMM (round-12 best) ----------------
// Grid = 512 blocks (2/CU). Block b: W-half = b&1 (64 KB swizzled LDS), mslice = b>>1.
// Wave reg-caches its 64x256 B-panel (32 bf16x8); main loop has NO LDS/barrier.
template <bool RELU>
__global__ __launch_bounds__(256, 2) void mfma_gemm(const unsigned short* __restrict__ A,
                                                    const unsigned short* __restrict__ Bt,
                                                    const float* __restrict__ bias,
                                                    unsigned short* __restrict__ C, int M) {
    __shared__ unsigned short Bs[128 * 256];   // [col][k] swizzled, 64 KB
    const int tid = threadIdx.x;
    const int wave = tid >> 6;
    const int lane = tid & 63;
    const int l15 = lane & 15;
    const int g4 = lane >> 4;                  // 0..3
    const int half = blockIdx.x & 1;
    const int mslice = blockIdx.x >> 1;        // 0..255
    const int NT = (M + 15) / 16;

    {
        const char* gsrc = (const char*)&Bt[(size_t)half * 128 * 256];
#pragma unroll
        for (int jj = 0; jj < 16; ++jj) {
            int chunk = tid + jj * 256;
            int col = chunk >> 5;
            int kbyte = (chunk & 31) * 16;
            *reinterpret_cast<u16x8*>((char*)Bs + col * 512 + (kbyte ^ ((col & 7) << 4))) =
                *reinterpret_cast<const u16x8*>(gsrc + col * 512 + kbyte);
        }
    }
    __syncthreads();

    bf16x8 b[4][8];
#pragma unroll
    for (int n = 0; n < 4; ++n) {
        const int col = (wave & 1) * 64 + n * 16 + l15;
        const char* cbase = (const char*)Bs + col * 512;
        const int sw = (col & 7) << 4;
#pragma unroll
        for (int k8 = 0; k8 < 8; ++k8) {
            int kbyte = (k8 * 32 + g4 * 8) * 2;
            b[n][k8] = *reinterpret_cast<const bf16x8*>(cbase + (kbyte ^ sw));
        }
    }

    const int ncol0 = half * 128 + (wave & 1) * 64;
    float bv[4];
#pragma unroll
    for (int n = 0; n < 4; ++n) bv[n] = bias[ncol0 + n * 16 + l15];

    const int base = mslice * 2 + (wave >> 1);

    auto loadA = [&](bf16x8 (&a)[8], int t) {
        int r = t * 16 + l15;
        if (r >= M) r = M - 1;
        const unsigned short* arow = &A[(size_t)r * 256];
#pragma unroll
        for (int k8 = 0; k8 < 8; ++k8)
            a[k8] = *reinterpret_cast<const bf16x8*>(arow + k8 * 32 + g4 * 8);
    };

    auto computeStore = [&](bf16x8 (&a)[8], int t) {
        f32x4 acc[4] = {};
#pragma unroll
        for (int k8 = 0; k8 < 8; ++k8)
#pragma unroll
            for (int n = 0; n < 4; ++n)
                acc[n] = __builtin_amdgcn_mfma_f32_16x16x32_bf16(a[k8], b[n][k8], acc[n], 0, 0, 0);
        int r0 = t * 16 + g4 * 4;
#pragma unroll
        for (int n = 0; n < 4; ++n) {
            int col = ncol0 + n * 16 + l15;
#pragma unroll
            for (int r = 0; r < 4; ++r) {
                int row = r0 + r;
                if (row < M) {
                    float v = acc[n][r] + bv[n];
                    if (RELU) v = fmaxf(v, 0.f);
                    C[(size_t)row * 256 + col] = f2bf(v);
                }
            }
        }
    };

    bf16x8 a0[8], a1[8];
    int t = base;
    if (t >= NT) return;
    loadA(a0, t);
#pragma unroll 1
    for (int rep = 0; rep < 2; ++rep) {
        if (t >= NT) break;
        if (t + 512 < NT) loadA(a1, t + 512);
        computeStore(a0, t);
        t += 512;
        if (t >= NT) break;
        if (t + 512 < NT) loadA(a0, t + 512);
        computeStore(a1, t);
        t += 512;
    }
}

// ---------------- pooling ----------------
// pools bf16 rows (here: t) into f32 accumulator buffer via atomics
__global__ void pool_kernel(const ushort4* __restrict__ h4, const int* __restrict__ gstart,
                            float* __restrict__ pooled) {
    int g = blockIdx.x;
    int split = blockIdx.y;
    int lane = threadIdx.x;   // 0..63
    int lo = gstart[g], hi = gstart[g + 1];
    int cnt = hi - lo;
    int chunk = (cnt + PSPLITS - 1) / PSPLITS;
    int s0 = lo + split * chunk;
    int s1 = min(s0 + chunk, hi);
    if (s0 >= s1) return;
    float ax = 0.f, ay = 0.f, az = 0.f, aw = 0.f;
    for (int nd = s0; nd < s1; ++nd) {
        ushort4 v = h4[(size_t)nd * 64 + lane];
        ax += b2f(v.x); ay += b2f(v.y); az += b2f(v.z); aw += b2f(v.w);
    }
    float* p = &pooled[(size_t)g * DIM + lane * 4];
    atomicAdd(p + 0, ax);
    atomicAdd(p + 1, ay);
    atomicAdd(p + 2, az);
    atomicAdd(p + 3, aw);
}

// final: pooled = Tp@W2 + cnt*b2 (f32), out = pooled@Wout + bout
__global__ void final_kernel(const float* __restrict__ Tp, const int* __restrict__ gstart,
                             const float* __restrict__ W2, const float* __restrict__ b2,
                             const float* __restrict__ Wout, const float* __restrict__ bout,
                             float* __restrict__ out, float* __restrict__ pooled) {
    __shared__ float tps[DIM];
    __shared__ float pl[DIM];
    int g = blockIdx.x;
    int tidx = threadIdx.x;    // 256
    float cnt = (float)(gstart[g + 1] - gstart[g]);
    tps[tidx] = Tp[(size_t)g * DIM + tidx];
    __syncthreads();
    float acc = cnt * b2[tidx];
    for (int d = 0; d < DIM; ++d)
        acc += tps[d] * W2[(size_t)d * DIM + tidx];
    pooled[(size_t)g * DIM + tidx] = acc;
    pl[tidx] = acc;
    __syncthreads();
    if (tidx < DOUT) {
        float o = bout[tidx];
        for (int d = 0; d < DIM; ++d)
            o += pl[d] * Wout[(size_t)d * DOUT + tidx];
        out[(size_t)g * DOUT + tidx] = o;
    }
}

// ---------------- launch ----------------
extern "C" void kernel_launch(void* const* d_in, const int* in_sizes, int n_in,
                              void* d_out, int out_size, void* d_ws, size_t ws_size,
                              hipStream_t stream) {
    const float* x    = (const float*)d_in[0];
    const int*   esrc = (const int*)d_in[1];
    const int*   edst = (const int*)d_in[2];
    const int*   bids = (const int*)d_in[3];
    const float* W1   = (const float*)d_in[4];
    const float* b1   = (const float*)d_in[5];
    const float* W2   = (const float*)d_in[6];
    const float* b2   = (const float*)d_in[7];
    const float* Wout = (const float*)d_in[8];
    const float* bout = (const float*)d_in[9];

    const int N = in_sizes[3];             // 20000
    const int E = in_sizes[1];             // 320000
    const int L = in_sizes[5] / DIM;       // 4
    const int G = out_size / (DOUT + DIM); // 128
    const int NB = (N + 255) / 256;        // scan blocks (79)

    char* ws = (char*)d_ws;
    size_t off = 0;
    auto carve = [&](size_t bytes) -> char* {
        char* p = ws + off;
        off = (off + bytes + 255) & ~(size_t)255;
        return p;
    };
    int* row_ptr = (int*)carve((size_t)(N + 1) * sizeof(int));
    int* cursor  = (int*)carve((size_t)N * sizeof(int));
    int* perm    = (int*)carve((size_t)E * sizeof(int));
    int* gstart  = (int*)carve((size_t)(G + 1) * sizeof(int));
    int* bsum    = (int*)carve((size_t)256 * sizeof(int));
    float* Tp    = (float*)carve((size_t)G * DIM * sizeof(float));
    unsigned short* h   = (unsigned short*)carve((size_t)N * DIM * 2);
    unsigned short* z   = (unsigned short*)carve((size_t)N * DIM * 2);
    unsigned short* t   = (unsigned short*)carve((size_t)N * DIM * 2);
    unsigned short* wt1 = (unsigned short*)carve((size_t)L * DIM * DIM * 2);
    unsigned short* wt2 = (unsigned short*)carve((size_t)L * DIM * DIM * 2);
    (void)ws_size;

    // h = bf16(x); also zero CSR cursor
    cvt_zero_kernel<<<2048, 256, 0, stream>>>((const float4*)x, (ushort4*)h,
                                              N * (DIM / 4), cursor, N);

    // CSR build: hist -> 3-phase parallel scan (w/ gstart fused) -> scatter
    hist_kernel<<<(E + 255) / 256, 256, 0, stream>>>(edst, cursor, E);
    scan_blocksum<<<NB, 256, 0, stream>>>(cursor, bsum, N);
    scan_partials<<<1, 256, 0, stream>>>(bsum, row_ptr, NB, N, bids, gstart, G);
    scan_final<<<NB, 256, 0, stream>>>(cursor, row_ptr, bsum, N, Tp, G * DIM);
    scatter_kernel<<<(E + 255) / 256, 256, 0, stream>>>(esrc, edst, cursor, perm, E);

    // Wt = bf16(W^T) for both MLP weight sets, single dispatch
    {
        dim3 tgrid(DIM / 32, DIM / 32, 2 * L);
        dim3 tblk(32, 8);
        transpose_all<<<tgrid, tblk, 0, stream>>>(W1, wt1, W2, wt2, L);
    }

    for (int l = 0; l < L; ++l) {
        agg_kernel<<<(N + 3) / 4, 256, 0, stream>>>(h, row_ptr, perm, z, N);
        mfma_gemm<true><<<512, 256, 0, stream>>>(
            z, wt1 + (size_t)l * DIM * DIM, b1 + (size_t)l * DIM, t, N);
        if (l < L - 1)
            mfma_gemm<true><<<512, 256, 0, stream>>>(
                t, wt2 + (size_t)l * DIM * DIM, b2 + (size_t)l * DIM, h, N);
        // last layer: GEMM2 folded into pooled path (linearity of segment_sum)
    }

    float* outp   = (float*)d_out;
    float* pooled = outp + (size_t)G * DOUT;
    {
        dim3 pgrid(G, PSPLITS);
        pool_kernel<<<pgrid, 64, 0, stream>>>((const ushort4*)t, gstart, Tp);
    }
    final_kernel<<<G, 256, 0, stream>>>(Tp, gstart,
                                        W2 + (size_t)(L - 1) * DIM * DIM,
                                        b2 + (size_t)(L - 1) * DIM,
                                        Wout, bout, outp, pooled);
}